// Round 7
// baseline (250.992 us; speedup 1.0000x reference)
//
#include <hip/hip_runtime.h>
#include <math.h>

typedef unsigned short u16;
typedef float floatx4 __attribute__((ext_vector_type(4)));
typedef __bf16 bf16x8 __attribute__((ext_vector_type(8)));
typedef __bf16 bf16x4 __attribute__((ext_vector_type(4)));
typedef short s16x4 __attribute__((ext_vector_type(4)));
typedef u16 u16x4 __attribute__((ext_vector_type(4)));

#define BB 2
#define SS 2048
#define HH 1024
#define NHEAD 16

// fp32 -> bf16 RNE (manual, used in cvt kernel)
__device__ __forceinline__ u16 f2bf(float f) {
  union { float f; unsigned u; } a; a.f = f;
  unsigned r = a.u + 0x7fffu + ((a.u >> 16) & 1u);
  return (u16)(r >> 16);
}

// fp32 -> bf16 via HW cvt (hot paths)
__device__ __forceinline__ u16 bfbits(float f) {
  union { __bf16 h; u16 u; } c; c.h = (__bf16)f; return c.u;
}

__device__ __forceinline__ float bf2f(u16 u) {
  union { unsigned u; float f; } a; a.u = ((unsigned)u) << 16; return a.f;
}

// K=16 bf16 MFMA (legacy op, still on gfx950 per ISA §10) with name fallback
__device__ __forceinline__ floatx4 mfma16(s16x4 a, s16x4 b, floatx4 c) {
#if __has_builtin(__builtin_amdgcn_mfma_f32_16x16x16_bf16)
  return __builtin_amdgcn_mfma_f32_16x16x16_bf16(
      __builtin_bit_cast(bf16x4, a), __builtin_bit_cast(bf16x4, b), c, 0, 0, 0);
#else
  return __builtin_amdgcn_mfma_f32_16x16x16bf16_1k(a, b, c, 0, 0, 0);
#endif
}

// async global->LDS, 16B per lane; LDS dest must be wave-uniform base + lane*16
__device__ __forceinline__ void gload16(const u16* g, u16* l) {
  __builtin_amdgcn_global_load_lds((const __attribute__((address_space(1))) void*)g,
                                   (__attribute__((address_space(3))) void*)l, 16, 0, 0);
}

// ---------------------------------------------------------------------------
// fp32 -> bf16 conversion of pre_out (4M) + 4 weights (1M each) + mask->bias2
// bias2 = (1-mask) * -10000 * log2(e)  (exp2-domain mask bias)
// ---------------------------------------------------------------------------
__global__ __launch_bounds__(256) void cvt_all(
    const float* __restrict__ X, const float* __restrict__ Wq, const float* __restrict__ Wk,
    const float* __restrict__ Wv, const float* __restrict__ Wo, const float* __restrict__ mask,
    u16* __restrict__ Xb, u16* __restrict__ Wqb, u16* __restrict__ Wkb,
    u16* __restrict__ Wvb, u16* __restrict__ Wob, float* __restrict__ B2) {
  int i = blockIdx.x * 256 + threadIdx.x;   // each thread: 4 elements
  if (i >= (2 << 20)) {                     // mask -> bias2 (4096 floats)
    int off = i - (2 << 20);
    float4 m = ((const float4*)mask)[off];
    float4 o;
    o.x = (1.0f - m.x) * (-10000.0f * 1.44269504f);
    o.y = (1.0f - m.y) * (-10000.0f * 1.44269504f);
    o.z = (1.0f - m.z) * (-10000.0f * 1.44269504f);
    o.w = (1.0f - m.w) * (-10000.0f * 1.44269504f);
    ((float4*)B2)[off] = o;
    return;
  }
  const float* src; u16* dst; int off;
  if (i < (1 << 20)) { src = X; dst = Xb; off = i; }
  else {
    int j = i - (1 << 20);
    int m = j >> 18; off = j & ((1 << 18) - 1);
    src = (m == 0) ? Wq : (m == 1) ? Wk : (m == 2) ? Wv : Wo;
    dst = (m == 0) ? Wqb : (m == 1) ? Wkb : (m == 2) ? Wvb : Wob;
  }
  float4 v = ((const float4*)src)[off];
  u16x4 p; p.x = f2bf(v.x); p.y = f2bf(v.y); p.z = f2bf(v.z); p.w = f2bf(v.w);
  ((u16x4*)dst)[off] = p;
}

// ---------------------------------------------------------------------------
// Fused QKV GEMM (m97 structure): 128x128 tile, BK=32, 4 waves of 4x4 MFMAs.
// mat 0/1 -> Q,K bf16 [s][feature]; mat 2 -> V bf16 transposed [b,h,d,s].
// ---------------------------------------------------------------------------
__global__ __launch_bounds__(256) void qkv_gemm(
    const u16* __restrict__ X,
    const u16* __restrict__ Wq, const u16* __restrict__ Wk, const u16* __restrict__ Wv,
    const float* __restrict__ bq, const float* __restrict__ bk, const float* __restrict__ bv,
    u16* __restrict__ Qo, u16* __restrict__ Ko, u16* __restrict__ Vt) {
  __shared__ u16 As[128 * 32];
  __shared__ u16 Ws[128 * 32];

  const int tid = threadIdx.x;
  const int w = tid >> 6, lane = tid & 63, quad = lane >> 4, l15 = lane & 15;
  const int mat = blockIdx.x >> 3;
  const int col0 = (blockIdx.x & 7) * 128;
  const int row0 = blockIdx.y * 128;
  const u16* W = (mat == 0) ? Wq : (mat == 1) ? Wk : Wv;
  const float* bias = (mat == 0) ? bq : (mat == 1) ? bk : bv;

  const int c0 = tid, c1 = tid + 256;
  const int ar0 = c0 >> 2, al0 = ((c0 & 3) ^ (ar0 & 3)) * 8;
  const int ar1 = c1 >> 2, al1 = ((c1 & 3) ^ (ar1 & 3)) * 8;
  const u16* gA0 = X + (row0 + ar0) * HH + al0;
  const u16* gA1 = X + (row0 + ar1) * HH + al1;
  const u16* gW0 = W + (col0 + ar0) * HH + al0;
  const u16* gW1 = W + (col0 + ar1) * HH + al1;
  u16* lA0 = As + c0 * 8; u16* lA1 = As + c1 * 8;
  u16* lW0 = Ws + c0 * 8; u16* lW1 = Ws + c1 * 8;

  const int wm = (w >> 1) * 64, wn = (w & 1) * 64;
  const int sw = quad ^ (l15 & 3);
  const int aoff = (wm + l15) * 32 + sw * 8;
  const int boff = (wn + l15) * 32 + sw * 8;

  floatx4 acc[4][4];
#pragma unroll
  for (int i = 0; i < 4; i++)
#pragma unroll
    for (int j = 0; j < 4; j++) acc[i][j] = {0.f, 0.f, 0.f, 0.f};

  for (int k0 = 0; k0 < HH; k0 += 32) {
    __syncthreads();
    gload16(gA0 + k0, lA0);
    gload16(gA1 + k0, lA1);
    gload16(gW0 + k0, lW0);
    gload16(gW1 + k0, lW1);
    __syncthreads();
    bf16x8 af[4], bfr[4];
#pragma unroll
    for (int i = 0; i < 4; i++) af[i] = *(const bf16x8*)(As + aoff + i * 512);
#pragma unroll
    for (int j = 0; j < 4; j++) bfr[j] = *(const bf16x8*)(Ws + boff + j * 512);
#pragma unroll
    for (int i = 0; i < 4; i++)
#pragma unroll
      for (int j = 0; j < 4; j++)
        acc[i][j] = __builtin_amdgcn_mfma_f32_16x16x32_bf16(af[i], bfr[j], acc[i][j], 0, 0, 0);
  }

  const int rb = row0 + wm + quad * 4;
  if (mat < 2) {
    u16* O = (mat == 0) ? Qo : Ko;
#pragma unroll
    for (int j = 0; j < 4; j++) {
      const int col = col0 + wn + j * 16 + l15;
      const float bj = bias[col];
#pragma unroll
      for (int i = 0; i < 4; i++) {
        const int r0 = rb + i * 16;
#pragma unroll
        for (int r = 0; r < 4; r++)
          O[(r0 + r) * HH + col] = bfbits(acc[i][j][r] + bj);
      }
    }
  } else {
#pragma unroll
    for (int j = 0; j < 4; j++) {
      const int col = col0 + wn + j * 16 + l15;
      const float bj = bias[col];
      const int h = col >> 6, d = col & 63;
#pragma unroll
      for (int i = 0; i < 4; i++) {
        const int m0 = rb + i * 16;
        const int b = m0 >> 11, s = m0 & 2047;
        u16x4 pk;
#pragma unroll
        for (int r = 0; r < 4; r++) pk[r] = bfbits(acc[i][j][r] + bj);
        *(u16x4*)(Vt + (((b * NHEAD + h) * 64 + d) * SS + s)) = pk;
      }
    }
  }
}

// ---------------------------------------------------------------------------
// Output projection GEMM: Y[4096,1024] fp32 = Ab @ Wo^T + bo
// ---------------------------------------------------------------------------
__global__ __launch_bounds__(256) void oproj_gemm(
    const u16* __restrict__ A, const u16* __restrict__ W,
    const float* __restrict__ bias, float* __restrict__ Y) {
  __shared__ u16 As[128 * 32];
  __shared__ u16 Ws[128 * 32];

  const int tid = threadIdx.x;
  const int w = tid >> 6, lane = tid & 63, quad = lane >> 4, l15 = lane & 15;
  const int col0 = blockIdx.x * 128;
  const int row0 = blockIdx.y * 128;

  const int c0 = tid, c1 = tid + 256;
  const int ar0 = c0 >> 2, al0 = ((c0 & 3) ^ (ar0 & 3)) * 8;
  const int ar1 = c1 >> 2, al1 = ((c1 & 3) ^ (ar1 & 3)) * 8;
  const u16* gA0 = A + (row0 + ar0) * HH + al0;
  const u16* gA1 = A + (row0 + ar1) * HH + al1;
  const u16* gW0 = W + (col0 + ar0) * HH + al0;
  const u16* gW1 = W + (col0 + ar1) * HH + al1;
  u16* lA0 = As + c0 * 8; u16* lA1 = As + c1 * 8;
  u16* lW0 = Ws + c0 * 8; u16* lW1 = Ws + c1 * 8;

  const int wm = (w >> 1) * 64, wn = (w & 1) * 64;
  const int sw = quad ^ (l15 & 3);
  const int aoff = (wm + l15) * 32 + sw * 8;
  const int boff = (wn + l15) * 32 + sw * 8;

  floatx4 acc[4][4];
#pragma unroll
  for (int i = 0; i < 4; i++)
#pragma unroll
    for (int j = 0; j < 4; j++) acc[i][j] = {0.f, 0.f, 0.f, 0.f};

  for (int k0 = 0; k0 < HH; k0 += 32) {
    __syncthreads();
    gload16(gA0 + k0, lA0);
    gload16(gA1 + k0, lA1);
    gload16(gW0 + k0, lW0);
    gload16(gW1 + k0, lW1);
    __syncthreads();
    bf16x8 af[4], bfr[4];
#pragma unroll
    for (int i = 0; i < 4; i++) af[i] = *(const bf16x8*)(As + aoff + i * 512);
#pragma unroll
    for (int j = 0; j < 4; j++) bfr[j] = *(const bf16x8*)(Ws + boff + j * 512);
#pragma unroll
    for (int i = 0; i < 4; i++)
#pragma unroll
      for (int j = 0; j < 4; j++)
        acc[i][j] = __builtin_amdgcn_mfma_f32_16x16x32_bf16(af[i], bfr[j], acc[i][j], 0, 0, 0);
  }

  const int rb = row0 + wm + quad * 4;
#pragma unroll
  for (int j = 0; j < 4; j++) {
    const int col = col0 + wn + j * 16 + l15;
    const float bj = bias[col];
#pragma unroll
    for (int i = 0; i < 4; i++) {
      const int r0 = rb + i * 16;
#pragma unroll
      for (int r = 0; r < 4; r++)
        Y[(r0 + r) * HH + col] = acc[i][j][r] + bj;
    }
  }
}

// ---------------------------------------------------------------------------
// MFMA flash attention, transposed dataflow, split-K 2-way, no-max exp2
// softmax, K/V double-buffered (1 barrier/iter, DMA overlaps compute).
//   ST = K·Q^T  (16x16x32, swap operands; C-layout [key=quad*4+r][q=l15])
//   P^T = exp2(ST*c + bias2)  -- already in B-operand layout for K=16 MFMA
//   O^T = V^T·P^T (16x16x16; A-frags = b64 reads from Vt tile rows)
// No P LDS round-trip. Grid (16 qtiles x 128 rows, 32 bh, 2 splits); 4 waves,
// wave owns 32 q rows. Partials (unnormalized O, l) combine by addition.
// ---------------------------------------------------------------------------
#define QT 128

__global__ __launch_bounds__(256) void attn_mfma(
    const u16* __restrict__ Q, const u16* __restrict__ K, const u16* __restrict__ Vt,
    const float* __restrict__ B2,
    u16* __restrict__ Po0, u16* __restrict__ Po1,
    float* __restrict__ L0, float* __restrict__ L1) {
  __shared__ u16 UQ[QT * 64];       // 16 KB
  __shared__ u16 Ks[2][64 * 64];    // 2 x 8 KB
  __shared__ u16 Vs[2][64 * 64];    // 2 x 8 KB

  const int qt = blockIdx.x, bh = blockIdx.y, split = blockIdx.z;
  const int b = bh >> 4, h = bh & 15;
  const int tid = threadIdx.x;
  const int w = tid >> 6, lane = tid & 63, quad = lane >> 4, l15 = lane & 15;
  const int sw = l15 & 7;

  u16* Po = split ? Po1 : Po0;
  float* Lp = split ? L1 : L0;

  const int qbase  = (b * SS + qt * QT) * HH + h * 64;
  const int kvbase = (b * SS) * HH + h * 64;
  const int vtbase = (b * NHEAD + h) * 64 * SS;
  const int kt0 = split * 16;

  // stage Q tile (chunk swizzle pc = lc ^ (row&7)) + prologue K/V (it=0, buf 0)
#pragma unroll
  for (int i = 0; i < 4; i++) {
    const int c = tid + i * 256;
    const int r = c >> 3, lc = (c & 7) ^ (r & 7);
    gload16(Q + qbase + r * HH + lc * 8, UQ + c * 8);
  }
#pragma unroll
  for (int i = 0; i < 2; i++) {
    const int c = tid + i * 256;
    const int r = c >> 3, lc = (c & 7) ^ (r & 7);
    gload16(K + kvbase + (kt0 * 64 + r) * HH + lc * 8, Ks[0] + c * 8);
    gload16(Vt + vtbase + r * SS + kt0 * 64 + lc * 8, Vs[0] + c * 8);
  }
  __syncthreads();

  // hoist Q fragments (B-operand: lane q=l15, elems d=quad*8+j and 32+quad*8+j)
  bf16x8 aQ[2][2];
#pragma unroll
  for (int mt = 0; mt < 2; mt++) {
    const u16* qr = UQ + (w * 32 + mt * 16 + l15) * 64;
    aQ[mt][0] = *(const bf16x8*)(qr + ((quad ^ sw) * 8));
    aQ[mt][1] = *(const bf16x8*)(qr + (((4 + quad) ^ sw) * 8));
  }

  floatx4 o[2][4];
#pragma unroll
  for (int mt = 0; mt < 2; mt++)
#pragma unroll
    for (int dt = 0; dt < 4; dt++) o[mt][dt] = {0.f, 0.f, 0.f, 0.f};
  float lp[2] = {0.f, 0.f};
  const float* B2row = B2 + b * SS;

  for (int it = 0; it < 16; it++) {
    const int cur = it & 1;
    __syncthreads();  // drains this iter's DMA (auto vmcnt0); fences buf cur^1
    if (it < 15) {    // prefetch next tile into the other buffer
      const int kt = kt0 + it + 1;
#pragma unroll
      for (int i = 0; i < 2; i++) {
        const int c = tid + i * 256;
        const int r = c >> 3, lc = (c & 7) ^ (r & 7);
        gload16(K + kvbase + (kt * 64 + r) * HH + lc * 8, Ks[cur ^ 1] + c * 8);
        gload16(Vt + vtbase + r * SS + kt * 64 + lc * 8, Vs[cur ^ 1] + c * 8);
      }
    }
    const int kt = kt0 + it;

    // ST = K·Q^T : C-layout row=key(quad*4+r), col=q(l15)
    floatx4 st[2][4];
#pragma unroll
    for (int kb = 0; kb < 4; kb++) {
      const u16* kr = Ks[cur] + (kb * 16 + l15) * 64;
      bf16x8 kf0 = *(const bf16x8*)(kr + ((quad ^ sw) * 8));
      bf16x8 kf1 = *(const bf16x8*)(kr + (((4 + quad) ^ sw) * 8));
#pragma unroll
      for (int mt = 0; mt < 2; mt++) {
        floatx4 z = {0.f, 0.f, 0.f, 0.f};
        z = __builtin_amdgcn_mfma_f32_16x16x32_bf16(kf0, aQ[mt][0], z, 0, 0, 0);
        st[mt][kb] = __builtin_amdgcn_mfma_f32_16x16x32_bf16(kf1, aQ[mt][1], z, 0, 0, 0);
      }
    }

    // P^T = exp2(ST*0.125*log2e + bias2[key]); key = kt*64+kb*16+quad*4+r
    s16x4 pb[2][4];
#pragma unroll
    for (int kb = 0; kb < 4; kb++) {
      const floatx4 bb = *(const floatx4*)(B2row + kt * 64 + kb * 16 + quad * 4);
#pragma unroll
      for (int mt = 0; mt < 2; mt++)
#pragma unroll
        for (int r = 0; r < 4; r++) {
          const float p = __builtin_amdgcn_exp2f(st[mt][kb][r] * 0.180336880f + bb[r]);
          lp[mt] += p;
          pb[mt][kb][r] = (short)bfbits(p);
        }
    }

    // O^T += V^T·P^T : A = Vs row (d), k=key (b64, swizzle-aware); B = pb
#pragma unroll
    for (int dt = 0; dt < 4; dt++) {
      const u16* vr = Vs[cur] + (dt * 16 + l15) * 64;
#pragma unroll
      for (int kb = 0; kb < 4; kb++) {
        const int pc = (2 * kb + (quad >> 1)) ^ sw;
        s16x4 va = *(const s16x4*)(vr + pc * 8 + (quad & 1) * 4);
#pragma unroll
        for (int mt = 0; mt < 2; mt++)
          o[mt][dt] = mfma16(va, pb[mt][kb], o[mt][dt]);
      }
    }
  }

  // l: per-lane partial covers this quad's 16 keys/iter -> reduce across quads
#pragma unroll
  for (int mt = 0; mt < 2; mt++) {
    float v = lp[mt];
    v += __shfl_xor(v, 16);
    v += __shfl_xor(v, 32);
    lp[mt] = v;
  }

  // write unnormalized partial O (O^T regs: d = dt*16+quad*4+r, q = l15) + l
#pragma unroll
  for (int mt = 0; mt < 2; mt++) {
    const int qrow = b * SS + qt * QT + w * 32 + mt * 16 + l15;
    u16* orow = Po + qrow * HH + h * 64;
#pragma unroll
    for (int dt = 0; dt < 4; dt++) {
      u16x4 pk;
#pragma unroll
      for (int r = 0; r < 4; r++) pk[r] = bfbits(o[mt][dt][r]);
      *(u16x4*)(orow + dt * 16 + quad * 4) = pk;
    }
    if (lane < 16) Lp[qrow * NHEAD + h] = lp[mt];
  }
}

// ---------------------------------------------------------------------------
// Combine split-K partials: Ab = (Po0 + Po1) / (l0 + l1)   (bf16 out, in-place
// over Po0's storage). Each thread: 4 contiguous elements at fixed (row, h).
// ---------------------------------------------------------------------------
__global__ __launch_bounds__(256) void attn_combine(
    const u16* __restrict__ Po1, const float* __restrict__ L0,
    const float* __restrict__ L1, u16* __restrict__ Ab /* = Po0 */) {
  const int idx = blockIdx.x * 256 + threadIdx.x;  // 4 elements each
  const int i = idx * 4;
  const int row = i >> 10;          // b*SS + s
  const int h = (i & 1023) >> 6;    // head
  const float inv = 1.0f / (L0[row * NHEAD + h] + L1[row * NHEAD + h]);
  u16x4 a = ((const u16x4*)Ab)[idx];
  u16x4 c = ((const u16x4*)Po1)[idx];
  u16x4 o;
#pragma unroll
  for (int k = 0; k < 4; k++) o[k] = bfbits((bf2f(a[k]) + bf2f(c[k])) * inv);
  ((u16x4*)Ab)[idx] = o;
}

// ---------------------------------------------------------------------------
// out = LayerNorm(x0 + y) * w + b
// ---------------------------------------------------------------------------
__device__ __forceinline__ float block_sum256(float v) {
  __shared__ float sb[4];
#pragma unroll
  for (int o = 1; o < 64; o <<= 1) v += __shfl_xor(v, o);
  if ((threadIdx.x & 63) == 0) sb[threadIdx.x >> 6] = v;
  __syncthreads();
  float r = sb[0] + sb[1] + sb[2] + sb[3];
  __syncthreads();
  return r;
}

__global__ __launch_bounds__(256) void add_layernorm(
    const float* __restrict__ x0, const float* __restrict__ y,
    const float* __restrict__ w, const float* __restrict__ b,
    float* __restrict__ out) {
  const int row = blockIdx.x;
  const int t = threadIdx.x;
  const float* xr = x0 + (size_t)row * HH;
  const float* yr = y + (size_t)row * HH;

  float v[4];
  float sum = 0.f;
#pragma unroll
  for (int i = 0; i < 4; i++) {
    int idx = t + i * 256;
    v[i] = xr[idx] + yr[idx];
    sum += v[i];
  }
  float mean = block_sum256(sum) * (1.0f / HH);

  float sq = 0.f;
#pragma unroll
  for (int i = 0; i < 4; i++) {
    float d = v[i] - mean;
    sq += d * d;
  }
  float var = block_sum256(sq) * (1.0f / HH);
  float inv = rsqrtf(var + 1e-12f);

#pragma unroll
  for (int i = 0; i < 4; i++) {
    int idx = t + i * 256;
    out[(size_t)row * HH + idx] = w[idx] * ((v[i] - mean) * inv) + b[idx];
  }
}

// ---------------------------------------------------------------------------
extern "C" void kernel_launch(void* const* d_in, const int* in_sizes, int n_in,
                              void* d_out, int out_size, void* d_ws, size_t ws_size,
                              hipStream_t stream) {
  const float* pre_out = (const float*)d_in[0];
  const float* mask    = (const float*)d_in[1];
  const float* Wq = (const float*)d_in[2];
  const float* bq = (const float*)d_in[3];
  const float* Wk = (const float*)d_in[4];
  const float* bk = (const float*)d_in[5];
  const float* Wv = (const float*)d_in[6];
  const float* bv = (const float*)d_in[7];
  const float* Wo = (const float*)d_in[8];
  const float* bo = (const float*)d_in[9];
  const float* ln_w = (const float*)d_in[10];
  const float* ln_b = (const float*)d_in[11];
  float* out = (float*)d_out;

  // workspace layout (~64 MB)
  u16* Xb  = (u16*)d_ws;                // 4M u16
  u16* Wqb = Xb + (4 << 20);            // 1M
  u16* Wkb = Wqb + (1 << 20);
  u16* Wvb = Wkb + (1 << 20);
  u16* Wob = Wvb + (1 << 20);
  u16* Qb  = Wob + (1 << 20);           // 4M
  u16* Kb  = Qb + (4 << 20);            // 4M
  u16* Vtb = Kb + (4 << 20);            // 4M
  u16* Ab  = Vtb + (4 << 20);           // 4M  (split-0 partial O, then combined)
  float* Yb = (float*)(Ab + (4 << 20)); // 4M fp32 (oproj out; hosts attn partials first)
  float* B2 = Yb + (4 << 20);           // 4096 fp32 (mask bias, exp2 domain)

  // attn split-K partials inside the dead-until-oproj Yb region:
  u16* Po1  = (u16*)Yb;                 // 4M u16 = 8 MB
  float* L0 = (float*)(Po1 + (4 << 20));// 64K fp32
  float* L1 = L0 + (BB * SS * NHEAD);   // 64K fp32

  cvt_all<<<8196, 256, 0, stream>>>(pre_out, Wq, Wk, Wv, Wo, mask,
                                    Xb, Wqb, Wkb, Wvb, Wob, B2);

  qkv_gemm<<<dim3(24, 32), 256, 0, stream>>>(Xb, Wqb, Wkb, Wvb, bq, bk, bv, Qb, Kb, Vtb);

  attn_mfma<<<dim3(SS / QT, BB * NHEAD, 2), 256, 0, stream>>>(Qb, Kb, Vtb, B2,
                                                              Ab, Po1, L0, L1);

  attn_combine<<<4096, 256, 0, stream>>>(Po1, L0, L1, Ab);

  oproj_gemm<<<dim3(8, 32), 256, 0, stream>>>(Ab, Wob, bo, Yb);

  add_layernorm<<<BB * SS, 256, 0, stream>>>(pre_out, Yb, ln_w, ln_b, out);
}

// Round 8
// 231.902 us; speedup vs baseline: 1.0823x; 1.0823x over previous
//
#include <hip/hip_runtime.h>
#include <math.h>

typedef unsigned short u16;
typedef float floatx4 __attribute__((ext_vector_type(4)));
typedef __bf16 bf16x8 __attribute__((ext_vector_type(8)));
typedef u16 u16x4 __attribute__((ext_vector_type(4)));

#define BB 2
#define SS 2048
#define HH 1024
#define NHEAD 16

// fp32 -> bf16 RNE (manual, used in cvt kernel)
__device__ __forceinline__ u16 f2bf(float f) {
  union { float f; unsigned u; } a; a.f = f;
  unsigned r = a.u + 0x7fffu + ((a.u >> 16) & 1u);
  return (u16)(r >> 16);
}

// fp32 -> bf16 via HW cvt (hot paths)
__device__ __forceinline__ u16 bfbits(float f) {
  union { __bf16 h; u16 u; } c; c.h = (__bf16)f; return c.u;
}

// async global->LDS, 16B per lane; LDS dest must be wave-uniform base + lane*16
__device__ __forceinline__ void gload16(const u16* g, u16* l) {
  __builtin_amdgcn_global_load_lds((const __attribute__((address_space(1))) void*)g,
                                   (__attribute__((address_space(3))) void*)l, 16, 0, 0);
}

// ---------------------------------------------------------------------------
// fp32 -> bf16 conversion of pre_out (4M) + 4 weights (1M each) + mask->bias2
// bias2 = (1-mask) * -10000 * log2(e)  (exp2-domain mask bias)
// ---------------------------------------------------------------------------
__global__ __launch_bounds__(256) void cvt_all(
    const float* __restrict__ X, const float* __restrict__ Wq, const float* __restrict__ Wk,
    const float* __restrict__ Wv, const float* __restrict__ Wo, const float* __restrict__ mask,
    u16* __restrict__ Xb, u16* __restrict__ Wqb, u16* __restrict__ Wkb,
    u16* __restrict__ Wvb, u16* __restrict__ Wob, float* __restrict__ B2) {
  int i = blockIdx.x * 256 + threadIdx.x;   // each thread: 4 elements
  if (i >= (2 << 20)) {                     // mask -> bias2 (4096 floats)
    int off = i - (2 << 20);
    float4 m = ((const float4*)mask)[off];
    float4 o;
    o.x = (1.0f - m.x) * (-10000.0f * 1.44269504f);
    o.y = (1.0f - m.y) * (-10000.0f * 1.44269504f);
    o.z = (1.0f - m.z) * (-10000.0f * 1.44269504f);
    o.w = (1.0f - m.w) * (-10000.0f * 1.44269504f);
    ((float4*)B2)[off] = o;
    return;
  }
  const float* src; u16* dst; int off;
  if (i < (1 << 20)) { src = X; dst = Xb; off = i; }
  else {
    int j = i - (1 << 20);
    int m = j >> 18; off = j & ((1 << 18) - 1);
    src = (m == 0) ? Wq : (m == 1) ? Wk : (m == 2) ? Wv : Wo;
    dst = (m == 0) ? Wqb : (m == 1) ? Wkb : (m == 2) ? Wvb : Wob;
  }
  float4 v = ((const float4*)src)[off];
  u16x4 p; p.x = f2bf(v.x); p.y = f2bf(v.y); p.z = f2bf(v.z); p.w = f2bf(v.w);
  ((u16x4*)dst)[off] = p;
}

// ---------------------------------------------------------------------------
// Fused QKV GEMM (m97 structure): 128x128 tile, BK=32, 4 waves of 4x4 MFMAs.
// mat 0/1 -> Q,K bf16 [s][feature]; mat 2 -> V bf16 transposed [b,h,d,s].
// ---------------------------------------------------------------------------
__global__ __launch_bounds__(256) void qkv_gemm(
    const u16* __restrict__ X,
    const u16* __restrict__ Wq, const u16* __restrict__ Wk, const u16* __restrict__ Wv,
    const float* __restrict__ bq, const float* __restrict__ bk, const float* __restrict__ bv,
    u16* __restrict__ Qo, u16* __restrict__ Ko, u16* __restrict__ Vt) {
  __shared__ u16 As[128 * 32];
  __shared__ u16 Ws[128 * 32];

  const int tid = threadIdx.x;
  const int w = tid >> 6, lane = tid & 63, quad = lane >> 4, l15 = lane & 15;
  const int mat = blockIdx.x >> 3;
  const int col0 = (blockIdx.x & 7) * 128;
  const int row0 = blockIdx.y * 128;
  const u16* W = (mat == 0) ? Wq : (mat == 1) ? Wk : Wv;
  const float* bias = (mat == 0) ? bq : (mat == 1) ? bk : bv;

  const int c0 = tid, c1 = tid + 256;
  const int ar0 = c0 >> 2, al0 = ((c0 & 3) ^ (ar0 & 3)) * 8;
  const int ar1 = c1 >> 2, al1 = ((c1 & 3) ^ (ar1 & 3)) * 8;
  const u16* gA0 = X + (row0 + ar0) * HH + al0;
  const u16* gA1 = X + (row0 + ar1) * HH + al1;
  const u16* gW0 = W + (col0 + ar0) * HH + al0;
  const u16* gW1 = W + (col0 + ar1) * HH + al1;
  u16* lA0 = As + c0 * 8; u16* lA1 = As + c1 * 8;
  u16* lW0 = Ws + c0 * 8; u16* lW1 = Ws + c1 * 8;

  const int wm = (w >> 1) * 64, wn = (w & 1) * 64;
  const int sw = quad ^ (l15 & 3);
  const int aoff = (wm + l15) * 32 + sw * 8;
  const int boff = (wn + l15) * 32 + sw * 8;

  floatx4 acc[4][4];
#pragma unroll
  for (int i = 0; i < 4; i++)
#pragma unroll
    for (int j = 0; j < 4; j++) acc[i][j] = {0.f, 0.f, 0.f, 0.f};

  for (int k0 = 0; k0 < HH; k0 += 32) {
    __syncthreads();
    gload16(gA0 + k0, lA0);
    gload16(gA1 + k0, lA1);
    gload16(gW0 + k0, lW0);
    gload16(gW1 + k0, lW1);
    __syncthreads();
    bf16x8 af[4], bfr[4];
#pragma unroll
    for (int i = 0; i < 4; i++) af[i] = *(const bf16x8*)(As + aoff + i * 512);
#pragma unroll
    for (int j = 0; j < 4; j++) bfr[j] = *(const bf16x8*)(Ws + boff + j * 512);
#pragma unroll
    for (int i = 0; i < 4; i++)
#pragma unroll
      for (int j = 0; j < 4; j++)
        acc[i][j] = __builtin_amdgcn_mfma_f32_16x16x32_bf16(af[i], bfr[j], acc[i][j], 0, 0, 0);
  }

  const int rb = row0 + wm + quad * 4;
  if (mat < 2) {
    u16* O = (mat == 0) ? Qo : Ko;
#pragma unroll
    for (int j = 0; j < 4; j++) {
      const int col = col0 + wn + j * 16 + l15;
      const float bj = bias[col];
#pragma unroll
      for (int i = 0; i < 4; i++) {
        const int r0 = rb + i * 16;
#pragma unroll
        for (int r = 0; r < 4; r++)
          O[(r0 + r) * HH + col] = bfbits(acc[i][j][r] + bj);
      }
    }
  } else {
#pragma unroll
    for (int j = 0; j < 4; j++) {
      const int col = col0 + wn + j * 16 + l15;
      const float bj = bias[col];
      const int h = col >> 6, d = col & 63;
#pragma unroll
      for (int i = 0; i < 4; i++) {
        const int m0 = rb + i * 16;
        const int b = m0 >> 11, s = m0 & 2047;
        u16x4 pk;
#pragma unroll
        for (int r = 0; r < 4; r++) pk[r] = bfbits(acc[i][j][r] + bj);
        *(u16x4*)(Vt + (((b * NHEAD + h) * 64 + d) * SS + s)) = pk;
      }
    }
  }
}

// ---------------------------------------------------------------------------
// Output projection GEMM: Y[4096,1024] fp32 = Ab @ Wo^T + bo
// 128x64 tiles (grid 16x32 = 512 blocks -> 2 blocks/CU); 4 waves of 2x4 MFMAs.
// ---------------------------------------------------------------------------
__global__ __launch_bounds__(256) void oproj_gemm(
    const u16* __restrict__ A, const u16* __restrict__ W,
    const float* __restrict__ bias, float* __restrict__ Y) {
  __shared__ u16 As[128 * 32];
  __shared__ u16 Ws[64 * 32];

  const int tid = threadIdx.x;
  const int w = tid >> 6, lane = tid & 63, quad = lane >> 4, l15 = lane & 15;
  const int col0 = blockIdx.x * 64;
  const int row0 = blockIdx.y * 128;

  const int c0 = tid, c1 = tid + 256;
  const int ar0 = c0 >> 2, al0 = ((c0 & 3) ^ (ar0 & 3)) * 8;
  const int ar1 = c1 >> 2, al1 = ((c1 & 3) ^ (ar1 & 3)) * 8;
  const u16* gA0 = A + (row0 + ar0) * HH + al0;
  const u16* gA1 = A + (row0 + ar1) * HH + al1;
  const u16* gW0 = W + (col0 + ar0) * HH + al0;   // 64 rows: ar0 in 0..63
  u16* lA0 = As + c0 * 8; u16* lA1 = As + c1 * 8;
  u16* lW0 = Ws + c0 * 8;

  const int wm = w * 32;
  const int sw = quad ^ (l15 & 3);
  const int aoff = (wm + l15) * 32 + sw * 8;
  const int boff = l15 * 32 + sw * 8;

  floatx4 acc[2][4];
#pragma unroll
  for (int i = 0; i < 2; i++)
#pragma unroll
    for (int j = 0; j < 4; j++) acc[i][j] = {0.f, 0.f, 0.f, 0.f};

  for (int k0 = 0; k0 < HH; k0 += 32) {
    __syncthreads();
    gload16(gA0 + k0, lA0);
    gload16(gA1 + k0, lA1);
    if (tid < 256) gload16(gW0 + k0, lW0);   // 256 chunks of W (all threads)
    __syncthreads();
    bf16x8 af[2], bfr[4];
#pragma unroll
    for (int i = 0; i < 2; i++) af[i] = *(const bf16x8*)(As + aoff + i * 512);
#pragma unroll
    for (int j = 0; j < 4; j++) bfr[j] = *(const bf16x8*)(Ws + boff + j * 512);
#pragma unroll
    for (int i = 0; i < 2; i++)
#pragma unroll
      for (int j = 0; j < 4; j++)
        acc[i][j] = __builtin_amdgcn_mfma_f32_16x16x32_bf16(af[i], bfr[j], acc[i][j], 0, 0, 0);
  }

  const int rb = row0 + wm + quad * 4;
#pragma unroll
  for (int j = 0; j < 4; j++) {
    const int col = col0 + j * 16 + l15;
    const float bj = bias[col];
#pragma unroll
    for (int i = 0; i < 2; i++) {
      const int r0 = rb + i * 16;
#pragma unroll
      for (int r = 0; r < 4; r++)
        Y[(r0 + r) * HH + col] = acc[i][j][r] + bj;
    }
  }
}

// ---------------------------------------------------------------------------
// MFMA flash attention (round-5 structure, 77us known-good), no-max exp2
// softmax. Grid (16 qtiles of 128 rows, 32 bh). 4 waves; wave owns 32 q rows.
// __launch_bounds__(256,3): cap regs for 3 blocks/CU co-residency.
// ---------------------------------------------------------------------------
#define QT 128

__global__ __launch_bounds__(256, 3) void attn_mfma(
    const u16* __restrict__ Q, const u16* __restrict__ K, const u16* __restrict__ Vt,
    const float* __restrict__ B2, u16* __restrict__ O) {
  __shared__ u16 UQ[9216];   // Qs [128][64] (8192) ∪ Ps (wave w at w*2304, [32][72])
  __shared__ u16 Ks[64 * 64];
  __shared__ u16 Vs[64 * 64];

  const int qt = blockIdx.x, bh = blockIdx.y;
  const int b = bh >> 4, h = bh & 15;
  const int tid = threadIdx.x;
  const int w = tid >> 6, lane = tid & 63, quad = lane >> 4, l15 = lane & 15;
  const int sw = l15 & 7;

  const int qbase  = (b * SS + qt * QT) * HH + h * 64;
  const int kvbase = (b * SS) * HH + h * 64;
  const int vtbase = (b * NHEAD + h) * 64 * SS;

  // stage Q tile: 128 rows x 128B, chunk swizzle pc = lc ^ (row&7)
#pragma unroll
  for (int i = 0; i < 4; i++) {
    const int c = tid + i * 256;
    const int r = c >> 3, lc = (c & 7) ^ (r & 7);
    gload16(Q + qbase + r * HH + lc * 8, UQ + c * 8);
  }
  __syncthreads();

  // hoist Q fragments (2 m-tiles x 2 k-halves) into registers
  bf16x8 aQ[2][2];
#pragma unroll
  for (int mt = 0; mt < 2; mt++) {
    const u16* qr = UQ + (w * 32 + mt * 16 + l15) * 64;
    aQ[mt][0] = *(const bf16x8*)(qr + ((quad ^ sw) * 8));
    aQ[mt][1] = *(const bf16x8*)(qr + (((4 + quad) ^ sw) * 8));
  }

  floatx4 o[2][4];
  float lp[2][4];
#pragma unroll
  for (int mt = 0; mt < 2; mt++)
#pragma unroll
    for (int j = 0; j < 4; j++) o[mt][j] = {0.f, 0.f, 0.f, 0.f};
#pragma unroll
  for (int mt = 0; mt < 2; mt++)
#pragma unroll
    for (int r = 0; r < 4; r++) lp[mt][r] = 0.f;

  u16* Pw = UQ + w * 2304;
  const float* B2row = B2 + b * SS;

  for (int kt = 0; kt < 32; kt++) {
    __syncthreads();   // all waves done reading Ks/Vs (iter 0: done reading Q)
#pragma unroll
    for (int i = 0; i < 2; i++) {
      const int c = tid + i * 256;
      const int r = c >> 3, lc = (c & 7) ^ (r & 7);
      gload16(K + kvbase + (kt * 64 + r) * HH + lc * 8, Ks + c * 8);
      gload16(Vt + vtbase + r * SS + kt * 64 + lc * 8, Vs + c * 8);
    }
    __syncthreads();

    // QK^T
    floatx4 s[2][4];
#pragma unroll
    for (int j = 0; j < 4; j++) {
      const u16* kr = Ks + (j * 16 + l15) * 64;
      bf16x8 b0 = *(const bf16x8*)(kr + ((quad ^ sw) * 8));
      bf16x8 b1 = *(const bf16x8*)(kr + (((4 + quad) ^ sw) * 8));
#pragma unroll
      for (int mt = 0; mt < 2; mt++) {
        floatx4 z = {0.f, 0.f, 0.f, 0.f};
        z = __builtin_amdgcn_mfma_f32_16x16x32_bf16(aQ[mt][0], b0, z, 0, 0, 0);
        s[mt][j] = __builtin_amdgcn_mfma_f32_16x16x32_bf16(aQ[mt][1], b1, z, 0, 0, 0);
      }
    }

    // p = 2^(s * 0.125*log2e + bias2); accumulate per-lane l partials
#pragma unroll
    for (int j = 0; j < 4; j++) {
      const float bb = B2row[kt * 64 + j * 16 + l15];
#pragma unroll
      for (int mt = 0; mt < 2; mt++)
#pragma unroll
        for (int r = 0; r < 4; r++) {
          const float p = __builtin_amdgcn_exp2f(s[mt][j][r] * 0.180336880f + bb);
          s[mt][j][r] = p;
          lp[mt][r] += p;
        }
    }

    // P -> LDS (C-layout rows mt*16+quad*4+r, stride 72)
#pragma unroll
    for (int mt = 0; mt < 2; mt++)
#pragma unroll
      for (int j = 0; j < 4; j++)
#pragma unroll
        for (int r = 0; r < 4; r++)
          Pw[(mt * 16 + quad * 4 + r) * 72 + j * 16 + l15] = bfbits(s[mt][j][r]);

    // PV (same-wave LDS RAW: ordered by lgkmcnt)
    bf16x8 pa[2][2];
#pragma unroll
    for (int mt = 0; mt < 2; mt++) {
      const u16* pr = Pw + (mt * 16 + l15) * 72;
      pa[mt][0] = *(const bf16x8*)(pr + quad * 8);
      pa[mt][1] = *(const bf16x8*)(pr + 32 + quad * 8);
    }
#pragma unroll
    for (int j = 0; j < 4; j++) {
      const u16* vr = Vs + (j * 16 + l15) * 64;
      bf16x8 v0 = *(const bf16x8*)(vr + ((quad ^ sw) * 8));
      bf16x8 v1 = *(const bf16x8*)(vr + (((4 + quad) ^ sw) * 8));
#pragma unroll
      for (int mt = 0; mt < 2; mt++) {
        o[mt][j] = __builtin_amdgcn_mfma_f32_16x16x32_bf16(pa[mt][0], v0, o[mt][j], 0, 0, 0);
        o[mt][j] = __builtin_amdgcn_mfma_f32_16x16x32_bf16(pa[mt][1], v1, o[mt][j], 0, 0, 0);
      }
    }
  }

  // final l reduction across the 16 lanes holding each row
#pragma unroll
  for (int mt = 0; mt < 2; mt++)
#pragma unroll
    for (int r = 0; r < 4; r++) {
      float v = lp[mt][r];
      v += __shfl_xor(v, 1); v += __shfl_xor(v, 2);
      v += __shfl_xor(v, 4); v += __shfl_xor(v, 8);
      lp[mt][r] = v;
    }

#pragma unroll
  for (int mt = 0; mt < 2; mt++) {
    const int orow0 = b * SS + qt * QT + w * 32 + mt * 16 + quad * 4;
#pragma unroll
    for (int r = 0; r < 4; r++) {
      const float inv = 1.0f / lp[mt][r];
#pragma unroll
      for (int j = 0; j < 4; j++)
        O[(orow0 + r) * HH + h * 64 + j * 16 + l15] = bfbits(o[mt][j][r] * inv);
    }
  }
}

// ---------------------------------------------------------------------------
// out = LayerNorm(x0 + y) * w + b
// ---------------------------------------------------------------------------
__device__ __forceinline__ float block_sum256(float v) {
  __shared__ float sb[4];
#pragma unroll
  for (int o = 1; o < 64; o <<= 1) v += __shfl_xor(v, o);
  if ((threadIdx.x & 63) == 0) sb[threadIdx.x >> 6] = v;
  __syncthreads();
  float r = sb[0] + sb[1] + sb[2] + sb[3];
  __syncthreads();
  return r;
}

__global__ __launch_bounds__(256) void add_layernorm(
    const float* __restrict__ x0, const float* __restrict__ y,
    const float* __restrict__ w, const float* __restrict__ b,
    float* __restrict__ out) {
  const int row = blockIdx.x;
  const int t = threadIdx.x;
  const float* xr = x0 + (size_t)row * HH;
  const float* yr = y + (size_t)row * HH;

  float v[4];
  float sum = 0.f;
#pragma unroll
  for (int i = 0; i < 4; i++) {
    int idx = t + i * 256;
    v[i] = xr[idx] + yr[idx];
    sum += v[i];
  }
  float mean = block_sum256(sum) * (1.0f / HH);

  float sq = 0.f;
#pragma unroll
  for (int i = 0; i < 4; i++) {
    float d = v[i] - mean;
    sq += d * d;
  }
  float var = block_sum256(sq) * (1.0f / HH);
  float inv = rsqrtf(var + 1e-12f);

#pragma unroll
  for (int i = 0; i < 4; i++) {
    int idx = t + i * 256;
    out[(size_t)row * HH + idx] = w[idx] * ((v[i] - mean) * inv) + b[idx];
  }
}

// ---------------------------------------------------------------------------
extern "C" void kernel_launch(void* const* d_in, const int* in_sizes, int n_in,
                              void* d_out, int out_size, void* d_ws, size_t ws_size,
                              hipStream_t stream) {
  const float* pre_out = (const float*)d_in[0];
  const float* mask    = (const float*)d_in[1];
  const float* Wq = (const float*)d_in[2];
  const float* bq = (const float*)d_in[3];
  const float* Wk = (const float*)d_in[4];
  const float* bk = (const float*)d_in[5];
  const float* Wv = (const float*)d_in[6];
  const float* bv = (const float*)d_in[7];
  const float* Wo = (const float*)d_in[8];
  const float* bo = (const float*)d_in[9];
  const float* ln_w = (const float*)d_in[10];
  const float* ln_b = (const float*)d_in[11];
  float* out = (float*)d_out;

  // workspace layout
  u16* Xb  = (u16*)d_ws;                // 4M u16
  u16* Wqb = Xb + (4 << 20);            // 1M
  u16* Wkb = Wqb + (1 << 20);
  u16* Wvb = Wkb + (1 << 20);
  u16* Wob = Wvb + (1 << 20);
  u16* Qb  = Wob + (1 << 20);           // 4M
  u16* Kb  = Qb + (4 << 20);            // 4M
  u16* Vtb = Kb + (4 << 20);            // 4M
  u16* Ab  = Vtb + (4 << 20);           // 4M
  float* Yb = (float*)(Ab + (4 << 20)); // 4M fp32
  float* B2 = Yb + (4 << 20);           // 4096 fp32 (mask bias, exp2 domain)

  cvt_all<<<8196, 256, 0, stream>>>(pre_out, Wq, Wk, Wv, Wo, mask,
                                    Xb, Wqb, Wkb, Wvb, Wob, B2);

  qkv_gemm<<<dim3(24, 32), 256, 0, stream>>>(Xb, Wqb, Wkb, Wvb, bq, bk, bv, Qb, Kb, Vtb);

  attn_mfma<<<dim3(SS / QT, BB * NHEAD), 256, 0, stream>>>(Qb, Kb, Vtb, B2, Ab);

  oproj_gemm<<<dim3(16, 32), 256, 0, stream>>>(Ab, Wob, bo, Yb);

  add_layernorm<<<BB * SS, 256, 0, stream>>>(pre_out, Yb, ln_w, ln_b, out);
}